// Round 4
// baseline (258.959 us; speedup 1.0000x reference)
//
#include <hip/hip_runtime.h>
#include <math.h>

#define N_NODES 50000
#define N_EDGES 800000
#define NBK 196          // dst buckets of 256 nodes: bucket = dst >> 8
#define BCAP 6144        // max edges per bucket handled in LDS (mean 4082, sigma 64)

typedef short short8 __attribute__((ext_vector_type(8)));
typedef float f32x4 __attribute__((ext_vector_type(4)));
typedef float f32x2 __attribute__((ext_vector_type(2)));

// ---------------- bf16 / fp8 helpers ----------------
__device__ inline unsigned short f2bf(float v) {
  unsigned u = __float_as_uint(v);
  u += 0x7FFFu + ((u >> 16) & 1u);  // round-to-nearest-even
  return (unsigned short)(u >> 16);
}
__device__ inline float bf2f(unsigned short b) {
  return __uint_as_float(((unsigned)b) << 16);
}
__device__ inline float bflo(unsigned u) { return __uint_as_float(u << 16); }
__device__ inline float bfhi(unsigned u) { return __uint_as_float(u & 0xFFFF0000u); }
// fp8 e4m3 (OCP on gfx950); decode selector must be an immediate -> template param.
__device__ inline unsigned char f2fp8(float v) {
  return (unsigned char)(__builtin_amdgcn_cvt_pk_fp8_f32(v, 0.f, 0, false) & 0xFF);
}
template <bool HI>
__device__ inline f32x2 fp8dec(unsigned u) {
  return __builtin_amdgcn_cvt_pk_f32_fp8(u, HI);
}

#define SCL 0.17677669529663687f   // 1/sqrt(32), folded into Wq/bq at prep

// ---------------- fused prep: weight concat/transpose + bucket histogram ----------------
#define W1_B 256      // 512*128 / 256
#define W2_B 64       // 128*128 / 256
__global__ void prep_fused(const float* __restrict__ Wq1, const float* __restrict__ Wk1,
                           const float* __restrict__ Wv1, const float* __restrict__ Ws1,
                           const float* __restrict__ bq1, const float* __restrict__ bk1,
                           const float* __restrict__ bv1, const float* __restrict__ bs1,
                           const float* __restrict__ Wq2, const float* __restrict__ Wk2,
                           const float* __restrict__ Wv2, const float* __restrict__ Ws2,
                           const float* __restrict__ bq2, const float* __restrict__ bk2,
                           const float* __restrict__ bv2, const float* __restrict__ bs2,
                           unsigned short* __restrict__ Wt1, float* __restrict__ bcat1,
                           unsigned short* __restrict__ Wt2, float* __restrict__ bcat2,
                           const int* __restrict__ ei, int* __restrict__ bhist, int E) {
  const int b = blockIdx.x, tid = threadIdx.x;
  if (b < W1_B) {
    int i = b * 256 + tid;   // over 512*128
    int c = i >> 7, k = i & 127;
    int mi = c >> 7, lc = c & 127;
    const float* W = (mi == 0) ? Wq1 : (mi == 1) ? Wk1 : (mi == 2) ? Wv1 : Ws1;
    float scl = (mi == 0) ? SCL : 1.f;
    Wt1[i] = f2bf(W[(size_t)k * 128 + lc] * scl);
    if (i < 512) {
      int bm = i >> 7, bl = i & 127;
      const float* bb = (bm == 0) ? bq1 : (bm == 1) ? bk1 : (bm == 2) ? bv1 : bs1;
      bcat1[i] = bb[bl] * ((bm == 0) ? SCL : 1.f);
    }
  } else if (b < W1_B + W2_B) {
    int i = (b - W1_B) * 256 + tid;  // over 128*128
    int c = i >> 7, k = i & 127;
    int mi = c >> 5, lc = c & 31;
    const float* W = (mi == 0) ? Wq2 : (mi == 1) ? Wk2 : (mi == 2) ? Wv2 : Ws2;
    float scl = (mi == 0) ? SCL : 1.f;
    Wt2[i] = f2bf(W[(size_t)k * 32 + lc] * scl);
    if (i < 128) {
      int bm = i >> 5, bl = i & 31;
      const float* bb = (bm == 0) ? bq2 : (bm == 1) ? bk2 : (bm == 2) ? bv2 : bs2;
      bcat2[i] = bb[bl] * ((bm == 0) ? SCL : 1.f);
    }
  } else {
    __shared__ int h[NBK];
    for (int i = tid; i < NBK; i += 256) h[i] = 0;
    __syncthreads();
    int e = (b - W1_B - W2_B) * 4096 + tid;
#pragma unroll
    for (int p = 0; p < 16; ++p, e += 256)
      if (e < E) atomicAdd(&h[ei[E + e] >> 8], 1);
    __syncthreads();
    for (int i = tid; i < NBK; i += 256)
      if (h[i]) atomicAdd(&bhist[i], h[i]);
  }
}

// ================= bucket scan =================
__global__ void bucket_scan(const int* __restrict__ bhist, int* __restrict__ boff,
                            int* __restrict__ bcur) {
  __shared__ int s[256];
  int t = threadIdx.x;
  int v = (t < NBK) ? bhist[t] : 0;
  s[t] = v;
  __syncthreads();
#pragma unroll
  for (int off = 1; off < 256; off <<= 1) {
    int u = (t >= off) ? s[t - off] : 0;
    __syncthreads();
    s[t] += u;
    __syncthreads();
  }
  if (t < NBK) {
    int excl = s[t] - v;
    boff[t] = excl;
    bcur[t] = excl;
  }
  if (t == NBK - 1) boff[NBK] = s[t];
}

// ================= FUSED: bucket_scatter (blocks [0,EB)) + conv1 GEMM (blocks [EB,EB+GB)) ====
// Scatter: LDS-aggregated two-phase bucket scatter -> contiguous slot chunks per block
// (write-combining friendly; WRITE_SIZE == logical 41.7 MB; verified r0/r1).
// GEMM: 64 rows x 512 cols in TWO 256-col passes (acc[4][4] per pass) so natural VGPR
// pressure is ~92-120 -- far below the 168 cap of __launch_bounds__(256,3). The cap is
// a pure occupancy hint here and CANNOT bind, so no toolchain can spill (the r2 compile
// showed a binding cap -4 regs collapsing the allocation to 84 VGPR + 115 MB scratch).
// LDS 52.2 KB -> 3 blocks/CU = 3 waves/SIMD is the true residency limit.
// pass0: waves 0,1 -> Q (cols 0-127, bf16), waves 2,3 -> K (128-255, fp8 even bytes)
// pass1: waves 0,1 -> V (256-383, fp8 odd bytes), waves 2,3 -> SK (384-511, reuse L[0])
// KV fp8 row (256 B/node): byte 4t+{0,1} = K[2t,2t+1], byte 4t+{2,3} = V[2t,2t+1].
// ebuck packed: (src<<8) | (dst & 255).
__global__ __launch_bounds__(256, 3) void scatter_gemm1(
    const int* __restrict__ ei, int* __restrict__ bcur, int* __restrict__ ebuck, int E, int EB,
    const float* __restrict__ X, const unsigned short* __restrict__ Wt,
    const float* __restrict__ bcat, unsigned short* __restrict__ Q1b,
    unsigned short* __restrict__ SK1, unsigned char* __restrict__ KV8, int M) {
  __shared__ __align__(16) unsigned char L[3][64 * 272];  // 52.2 KB
  const int tid = threadIdx.x;

  if ((int)blockIdx.x < EB) {
    // ---------- scatter path ----------
    int* lh = (int*)L[0];
    for (int i = tid; i < NBK; i += 256) lh[i] = 0;
    __syncthreads();
    const int e0 = blockIdx.x * 4096;
    int pks[16], bks[16];
#pragma unroll
    for (int p = 0; p < 16; ++p) {
      int e = e0 + p * 256 + tid;
      if (e < E) {
        int src = ei[e], dst = ei[E + e];
        pks[p] = (src << 8) | (dst & 255);
        bks[p] = dst >> 8;
        atomicAdd(&lh[bks[p]], 1);
      } else bks[p] = -1;
    }
    __syncthreads();
    for (int i = tid; i < NBK; i += 256)
      if (lh[i]) lh[i] = atomicAdd(&bcur[i], lh[i]);
    __syncthreads();
#pragma unroll
    for (int p = 0; p < 16; ++p) {
      if (bks[p] >= 0) {
        int slot = atomicAdd(&lh[bks[p]], 1);
        ebuck[slot] = pks[p];
      }
    }
    return;
  }

  // ---------- GEMM path (two passes, low register pressure) ----------
  unsigned short* As = (unsigned short*)L[0];             // stride 136 shorts
  const int bm = (blockIdx.x - EB) * 64;
  const int wave = tid >> 6, lane = tid & 63;
  const int lr = lane & 15, q = lane >> 4;

#pragma unroll
  for (int p = 0; p < 8; ++p) {
    int f = tid + p * 256;          // 0..2047 float4s
    int row = f >> 5, c4 = f & 31;
    int gm = bm + row; if (gm >= M) gm = 0;
    float4 v = *(const float4*)(X + (size_t)gm * 128 + c4 * 4);
    ushort4 o;
    o.x = f2bf(v.x); o.y = f2bf(v.y); o.z = f2bf(v.z); o.w = f2bf(v.w);
    *(ushort4*)&As[row * 136 + c4 * 4] = o;
  }
  __syncthreads();

#pragma unroll
  for (int pass = 0; pass < 2; ++pass) {
    const int colbase = pass * 256 + wave * 64;
    f32x4 acc[4][4];
#pragma unroll
    for (int i = 0; i < 4; ++i)
#pragma unroll
      for (int j = 0; j < 4; ++j) acc[i][j] = (f32x4){0.f, 0.f, 0.f, 0.f};

#pragma unroll
    for (int ks = 0; ks < 4; ++ks) {
      short8 af[4];
#pragma unroll
      for (int i = 0; i < 4; ++i)
        af[i] = *(short8*)&As[(i * 16 + lr) * 136 + ks * 32 + q * 8];
#pragma unroll
      for (int j = 0; j < 4; ++j) {
        short8 bf = *(const short8*)(Wt + (size_t)(colbase + j * 16 + lr) * 128 + ks * 32 + q * 8);
#pragma unroll
        for (int i = 0; i < 4; ++i)
          acc[i][j] = __builtin_amdgcn_mfma_f32_16x16x32_bf16(af[i], bf, acc[i][j], 0, 0, 0);
      }
    }

    float bj[4];
#pragma unroll
    for (int j = 0; j < 4; ++j) bj[j] = bcat[colbase + j * 16 + lr];

    if (pass == 0) {
      if (wave < 2) {          // Q cols 0..127 -> L[1] bf16
        unsigned short* Ls16 = (unsigned short*)L[1];
#pragma unroll
        for (int i = 0; i < 4; ++i)
#pragma unroll
          for (int r = 0; r < 4; ++r) {
            int row = i * 16 + q * 4 + r;
#pragma unroll
            for (int j = 0; j < 4; ++j)
              Ls16[row * 136 + wave * 64 + j * 16 + lr] = f2bf(acc[i][j][r] + bj[j]);
          }
      } else {                 // K dims 0..127 -> L[2] fp8 (voff 0)
        unsigned char* KLs = L[2];
#pragma unroll
        for (int i = 0; i < 4; ++i)
#pragma unroll
          for (int r = 0; r < 4; ++r) {
            int row = i * 16 + q * 4 + r;
#pragma unroll
            for (int j = 0; j < 4; ++j) {
              int d = (wave - 2) * 64 + j * 16 + lr;
              KLs[row * 272 + 4 * (d >> 1) + (d & 1)] = f2fp8(acc[i][j][r] + bj[j]);
            }
          }
      }
    } else {
      __syncthreads();         // all As (L[0]) reads complete before SK overwrites it
      if (wave < 2) {          // V dims 0..127 -> L[2] fp8 (voff 2)
        unsigned char* KLs = L[2];
#pragma unroll
        for (int i = 0; i < 4; ++i)
#pragma unroll
          for (int r = 0; r < 4; ++r) {
            int row = i * 16 + q * 4 + r;
#pragma unroll
            for (int j = 0; j < 4; ++j) {
              int d = wave * 64 + j * 16 + lr;
              KLs[row * 272 + 4 * (d >> 1) + 2 + (d & 1)] = f2fp8(acc[i][j][r] + bj[j]);
            }
          }
      } else {                 // SK cols 0..127 -> L[0] bf16 (As no longer needed)
        unsigned short* Ls16 = (unsigned short*)L[0];
#pragma unroll
        for (int i = 0; i < 4; ++i)
#pragma unroll
          for (int r = 0; r < 4; ++r) {
            int row = i * 16 + q * 4 + r;
#pragma unroll
            for (int j = 0; j < 4; ++j)
              Ls16[row * 136 + (wave - 2) * 64 + j * 16 + lr] = f2bf(acc[i][j][r] + bj[j]);
          }
      }
    }
  }
  __syncthreads();

#pragma unroll
  for (int p = 0; p < 4; ++p) {
    int f = tid + p * 256;
    int row = f >> 4, u = f & 15;
    int gr = bm + row;
    if (gr < M) {
      *(uint4*)(Q1b + (size_t)gr * 128 + u * 8) = *(uint4*)&((unsigned short*)L[1])[row * 136 + u * 8];
      *(uint4*)(KV8 + (size_t)gr * 256 + u * 16) = *(uint4*)&L[2][row * 272 + u * 16];
      *(uint4*)(SK1 + (size_t)gr * 128 + u * 8) = *(uint4*)&((unsigned short*)L[0])[row * 136 + u * 8];
    }
  }
}

// esrc stores src<<8 (byte offset into the 256B/node tables)
__global__ void bucket_csr(const int* __restrict__ ebuck, const int* __restrict__ boff,
                           int* __restrict__ rowptr, int* __restrict__ esrc, int N) {
  const int b = blockIdx.x;
  const int lo = boff[b], hi = boff[b + 1];
  const int cnt = hi - lo;
  __shared__ int hist[256];
  __shared__ int cur[256];
  __shared__ int sorted[BCAP];
  const int t = threadIdx.x;
  hist[t] = 0;
  __syncthreads();
  for (int i = t; i < cnt; i += 256) atomicAdd(&hist[ebuck[lo + i] & 255], 1);
  __syncthreads();
  int v = hist[t];
  sorted[t] = v;
  __syncthreads();
#pragma unroll
  for (int off = 1; off < 256; off <<= 1) {
    int u = (t >= off) ? sorted[t - off] : 0;
    __syncthreads();
    sorted[t] += u;
    __syncthreads();
  }
  int excl = sorted[t] - v;
  cur[t] = excl;
  int node = b * 256 + t;
  if (node <= N) rowptr[node] = lo + excl;
  __syncthreads();
  for (int i = t; i < cnt; i += 256) {
    int pk = ebuck[lo + i];
    int slot = atomicAdd(&cur[pk & 255], 1);
    if (slot < BCAP) sorted[slot] = pk;
    else esrc[lo + slot] = pk & 0xFFFFFF00;
  }
  __syncthreads();
  int lim = cnt < BCAP ? cnt : BCAP;
  for (int i = t; i < lim; i += 256) esrc[lo + i] = sorted[i] & 0xFFFFFF00;
}

// ======== FUSED conv1-attention + conv2-GEMM: 32 nodes/block, H never leaves LDS ========
// Phase A: 8 units (4 waves x 2 halves of 32 lanes); unit u computes nodes u+8k (k<4):
//   full conv1 attention (plain-exp softmax, fp8 K/V, 4 edges in flight) + skip + relu,
//   result written as bf16 ushort4 directly into Hs[row][ll*4] (stride 136 = gemm2's As).
//   Per-wave MLP unchanged vs old node_attn1 (2 units x 4 edges = 8 edges in flight).
// Phase B: gemm2 body on the 32 LDS rows (acc[2][2], 4 waves x 32 cols) -> C2 rows
//   [Q bf16 | KV fp8 | pad | H bf16] (identical layout; node_attn2 untouched).
// Saves: H1b 12.8 MB HBM write + 12.8 MB read, gemm2's launch + LDS staging pass.
// LDS 17.4 KB; no min-waves hint (r2 lesson: caps that can bind cause spill roulette).
__global__ __launch_bounds__(256) void attn1_gemm2(
    const int* __restrict__ rowptr, const int* __restrict__ esrc,
    const unsigned short* __restrict__ Qb, const unsigned char* __restrict__ KV8,
    const unsigned short* __restrict__ SK,
    const unsigned short* __restrict__ Wt, const float* __restrict__ bcat,
    unsigned char* __restrict__ C2b, int M) {
  __shared__ __align__(16) unsigned short Hs[32 * 136];   // 8.7 KB (A-tile for phase B)
  __shared__ __align__(16) unsigned char Lsb[32 * 272];   // 8.7 KB (C2 packing)
  const int tid = threadIdx.x, wave = tid >> 6, lane = tid & 63;
  const int half = lane >> 5, ll = lane & 31;
  const int unit = wave * 2 + half;        // 0..7
  const int bm = blockIdx.x * 32;

  const unsigned char* kvb = KV8 + ll * 8;
#pragma unroll
  for (int k = 0; k < 4; ++k) {
    const int row = unit + 8 * k;          // 0..31, all rows covered by 8 units
    const int node = bm + row;
    ushort4 h;
    if (node < M) {
      const int r0 = rowptr[node], r1 = rowptr[node + 1];
      uint2 qq = *(const uint2*)(Qb + (size_t)node * 128 + ll * 4);
      const float q0 = bflo(qq.x), q1 = bfhi(qq.x), q2 = bflo(qq.y), q3 = bfhi(qq.y);
      float l = 0.f, a0 = 0.f, a1 = 0.f, a2 = 0.f, a3 = 0.f;
      int j = r0;
      for (; j + 4 <= r1; j += 4) {
        int s0 = esrc[j], s1 = esrc[j + 1], s2 = esrc[j + 2], s3 = esrc[j + 3];
        uint2 u0 = *(const uint2*)(kvb + s0);
        uint2 u1 = *(const uint2*)(kvb + s1);
        uint2 u2 = *(const uint2*)(kvb + s2);
        uint2 u3 = *(const uint2*)(kvb + s3);
        f32x2 k0a = fp8dec<false>(u0.x), k0b = fp8dec<false>(u0.y);
        f32x2 k1a = fp8dec<false>(u1.x), k1b = fp8dec<false>(u1.y);
        f32x2 k2a = fp8dec<false>(u2.x), k2b = fp8dec<false>(u2.y);
        f32x2 k3a = fp8dec<false>(u3.x), k3b = fp8dec<false>(u3.y);
        float d0 = q0 * k0a.x + q1 * k0a.y + q2 * k0b.x + q3 * k0b.y;
        float d1 = q0 * k1a.x + q1 * k1a.y + q2 * k1b.x + q3 * k1b.y;
        float d2 = q0 * k2a.x + q1 * k2a.y + q2 * k2b.x + q3 * k2b.y;
        float d3 = q0 * k3a.x + q1 * k3a.y + q2 * k3b.x + q3 * k3b.y;
#pragma unroll
        for (int msk = 1; msk <= 4; msk <<= 1) {   // reduce within 8-lane head groups
          d0 += __shfl_xor(d0, msk);
          d1 += __shfl_xor(d1, msk);
          d2 += __shfl_xor(d2, msk);
          d3 += __shfl_xor(d3, msk);
        }
        float p0 = __expf(d0), p1 = __expf(d1), p2 = __expf(d2), p3 = __expf(d3);
        l += (p0 + p1) + (p2 + p3);
        f32x2 v0a = fp8dec<true>(u0.x), v0b = fp8dec<true>(u0.y);
        f32x2 v1a = fp8dec<true>(u1.x), v1b = fp8dec<true>(u1.y);
        f32x2 v2a = fp8dec<true>(u2.x), v2b = fp8dec<true>(u2.y);
        f32x2 v3a = fp8dec<true>(u3.x), v3b = fp8dec<true>(u3.y);
        a0 += p0 * v0a.x + p1 * v1a.x + p2 * v2a.x + p3 * v3a.x;
        a1 += p0 * v0a.y + p1 * v1a.y + p2 * v2a.y + p3 * v3a.y;
        a2 += p0 * v0b.x + p1 * v1b.x + p2 * v2b.x + p3 * v3b.x;
        a3 += p0 * v0b.y + p1 * v1b.y + p2 * v2b.y + p3 * v3b.y;
      }
      for (; j < r1; ++j) {   // tail, <=3 edges
        int s = esrc[j];
        uint2 u = *(const uint2*)(kvb + s);
        f32x2 ka = fp8dec<false>(u.x), kb = fp8dec<false>(u.y);
        float d = q0 * ka.x + q1 * ka.y + q2 * kb.x + q3 * kb.y;
#pragma unroll
        for (int msk = 1; msk <= 4; msk <<= 1) d += __shfl_xor(d, msk);
        float p = __expf(d);
        l += p;
        f32x2 va = fp8dec<true>(u.x), vb = fp8dec<true>(u.y);
        a0 += p * va.x; a1 += p * va.y; a2 += p * vb.x; a3 += p * vb.y;
      }
      float inv = (l > 0.f) ? 1.f / l : 0.f;
      uint2 sk = *(const uint2*)(SK + (size_t)node * 128 + ll * 4);
      float o0 = fmaxf(bflo(sk.x) + a0 * inv, 0.f);
      float o1 = fmaxf(bfhi(sk.x) + a1 * inv, 0.f);
      float o2 = fmaxf(bflo(sk.y) + a2 * inv, 0.f);
      float o3 = fmaxf(bfhi(sk.y) + a3 * inv, 0.f);
      h.x = f2bf(o0); h.y = f2bf(o1); h.z = f2bf(o2); h.w = f2bf(o3);
    } else {
      h.x = 0; h.y = 0; h.z = 0; h.w = 0;   // defined data for phase B (rows discarded)
    }
    *(ushort4*)&Hs[row * 136 + ll * 4] = h;
  }
  __syncthreads();

  // ---- phase B: gemm2 on the 32 LDS rows ----
  const int lr = lane & 15, q = lane >> 4;
  f32x4 acc[2][2];
#pragma unroll
  for (int i = 0; i < 2; ++i)
#pragma unroll
    for (int j = 0; j < 2; ++j) acc[i][j] = (f32x4){0.f, 0.f, 0.f, 0.f};

#pragma unroll
  for (int ks = 0; ks < 4; ++ks) {
    short8 af[2];
#pragma unroll
    for (int i = 0; i < 2; ++i)
      af[i] = *(short8*)&Hs[(i * 16 + lr) * 136 + ks * 32 + q * 8];
#pragma unroll
    for (int j = 0; j < 2; ++j) {
      short8 bf = *(const short8*)(Wt + (size_t)(wave * 32 + j * 16 + lr) * 128 + ks * 32 + q * 8);
#pragma unroll
      for (int i = 0; i < 2; ++i)
        acc[i][j] = __builtin_amdgcn_mfma_f32_16x16x32_bf16(af[i], bf, acc[i][j], 0, 0, 0);
    }
  }

  float bj[2];
#pragma unroll
  for (int j = 0; j < 2; ++j) bj[j] = bcat[wave * 32 + j * 16 + lr];
#pragma unroll
  for (int i = 0; i < 2; ++i)
#pragma unroll
    for (int r = 0; r < 4; ++r) {
      int row = i * 16 + q * 4 + r;
#pragma unroll
      for (int j = 0; j < 2; ++j) {
        int c = wave * 32 + j * 16 + lr;
        float val = acc[i][j][r] + bj[j];
        if (c < 32) {
          *(unsigned short*)&Lsb[row * 272 + 2 * c] = f2bf(val);
        } else if (c < 64) {
          int d = c - 32;
          Lsb[row * 272 + 64 + 4 * (d >> 1) + (d & 1)] = f2fp8(val);
        } else if (c < 96) {
          int d = c - 64;
          Lsb[row * 272 + 64 + 4 * (d >> 1) + 2 + (d & 1)] = f2fp8(val);
        } else {
          *(unsigned short*)&Lsb[row * 272 + 192 + 2 * (c - 96)] = f2bf(val);
        }
      }
    }
  __syncthreads();
#pragma unroll
  for (int p = 0; p < 8; ++p) {
    int idx = tid + p * 256;
    int row = idx >> 6, u = idx & 63;
    int gr = bm + row;
    if (gr < M) *(unsigned*)(C2b + (size_t)gr * 256 + u * 4) = *(const unsigned*)&Lsb[row * 272 + u * 4];
  }
}

// conv2 + fused relu/mean/Wo-dot: 16 lanes per edge (4 groups); x8 main loop; plain exp.
// Per node: t = dot(relu(skip + attn), Wo); block writes sum of its 4 nodes to pblock.
__global__ void node_attn2(const int* __restrict__ rowptr, const int* __restrict__ esrc,
                           const unsigned char* __restrict__ C2b, const float* __restrict__ Wo,
                           float* __restrict__ pblock, int n) {
  __shared__ float ps[4];
  int node = (blockIdx.x * blockDim.x + threadIdx.x) >> 6;
  int lane = threadIdx.x & 63;
  int wave = threadIdx.x >> 6;
  const int g = lane >> 4, gl = lane & 15;
  float t = 0.f;
  if (node < n) {
    const int r0 = rowptr[node], r1 = rowptr[node + 1];
    unsigned qu = *(const unsigned*)(C2b + (size_t)node * 256 + gl * 4);
    const float q0 = bflo(qu), q1 = bfhi(qu);
    float l = 0.f, a0 = 0.f, a1 = 0.f;
    const unsigned char* kvb = C2b + 64 + gl * 4;
    int j = r0;
    for (; j + 8 <= r1; j += 8) {
      int e = j + g * 2;
      int s0 = esrc[e], s1 = esrc[e + 1];
      unsigned u0 = *(const unsigned*)(kvb + s0);
      unsigned u1 = *(const unsigned*)(kvb + s1);
      f32x2 k0 = fp8dec<false>(u0), k1 = fp8dec<false>(u1);
      float d0 = q0 * k0.x + q1 * k0.y;
      float d1 = q0 * k1.x + q1 * k1.y;
#pragma unroll
      for (int msk = 1; msk <= 8; msk <<= 1) {
        d0 += __shfl_xor(d0, msk);
        d1 += __shfl_xor(d1, msk);
      }
      float p0 = __expf(d0), p1 = __expf(d1);
      l += p0 + p1;
      f32x2 v0 = fp8dec<true>(u0), v1 = fp8dec<true>(u1);
      a0 += p0 * v0.x + p1 * v1.x;
      a1 += p0 * v0.y + p1 * v1.y;
    }
    for (; j < r1; j += 4) {
      bool v = (j + g) < r1;
      int s = esrc[v ? j + g : r0];
      unsigned u = *(const unsigned*)(kvb + s);
      f32x2 kd = fp8dec<false>(u);
      float d = q0 * kd.x + q1 * kd.y;
#pragma unroll
      for (int msk = 1; msk <= 8; msk <<= 1) d += __shfl_xor(d, msk);
      float p = v ? __expf(d) : 0.f;
      l += p;
      f32x2 vd = fp8dec<true>(u);
      a0 += p * vd.x;
      a1 += p * vd.y;
    }
#pragma unroll
    for (int msk = 16; msk <= 32; msk <<= 1) {
      l  += __shfl_xor(l, msk);
      a0 += __shfl_xor(a0, msk);
      a1 += __shfl_xor(a1, msk);
    }
    float inv = (l > 0.f) ? 1.f / l : 0.f;
    unsigned hu = *(const unsigned*)(C2b + (size_t)node * 256 + 192 + gl * 4);
    float o0 = fmaxf(bflo(hu) + a0 * inv, 0.f);
    float o1 = fmaxf(bfhi(hu) + a1 * inv, 0.f);
    t = o0 * Wo[2 * gl] + o1 * Wo[2 * gl + 1];
    // reduce over 16 gl-lanes (all 64 lanes hold per-gl copies; masks stay within groups)
#pragma unroll
    for (int msk = 1; msk <= 8; msk <<= 1) t += __shfl_xor(t, msk);
  }
  if (lane == 0) ps[wave] = t;
  __syncthreads();
  if (threadIdx.x == 0) pblock[blockIdx.x] = ps[0] + ps[1] + ps[2] + ps[3];
}

// ---------------- final: sum per-block partials, scale, bias ----------------
__global__ void final_out(const float* __restrict__ pblock, const float* __restrict__ bo,
                          float* __restrict__ out, int nb, float invN) {
  __shared__ float s[256];
  float acc = 0.f;
  for (int i = threadIdx.x; i < nb; i += 256) acc += pblock[i];
  s[threadIdx.x] = acc;
  __syncthreads();
  for (int off = 128; off >= 1; off >>= 1) {
    if (threadIdx.x < off) s[threadIdx.x] += s[threadIdx.x + off];
    __syncthreads();
  }
  if (threadIdx.x == 0) out[0] = s[0] * invN + bo[0];
}

extern "C" void kernel_launch(void* const* d_in, const int* in_sizes, int n_in,
                              void* d_out, int out_size, void* d_ws, size_t ws_size,
                              hipStream_t stream) {
  const float* x   = (const float*)d_in[0];
  const int*   ei  = (const int*)d_in[1];  // [2, E]: row 0 = src, row 1 = dst
  const float* Wq1 = (const float*)d_in[2];  const float* bq1 = (const float*)d_in[3];
  const float* Wk1 = (const float*)d_in[4];  const float* bk1 = (const float*)d_in[5];
  const float* Wv1 = (const float*)d_in[6];  const float* bv1 = (const float*)d_in[7];
  const float* Ws1 = (const float*)d_in[8];  const float* bs1 = (const float*)d_in[9];
  const float* Wq2 = (const float*)d_in[10]; const float* bq2 = (const float*)d_in[11];
  const float* Wk2 = (const float*)d_in[12]; const float* bk2 = (const float*)d_in[13];
  const float* Wv2 = (const float*)d_in[14]; const float* bv2 = (const float*)d_in[15];
  const float* Ws2 = (const float*)d_in[16]; const float* bs2 = (const float*)d_in[17];
  const float* Wo  = (const float*)d_in[18]; const float* bo  = (const float*)d_in[19];

  char* ws = (char*)d_ws;
  const int N = N_NODES, E = N_EDGES;
  const int GB = (N + 63) / 64;
  const int GB2 = (N + 31) / 32;   // 1563 fused attn1+gemm2 blocks (32 nodes each)
  const int EB = (E + 4095) / 4096;
  const int AB = (N * 64) / 256;   // 12500 attn blocks

  // buffers
  unsigned short* Q1b = (unsigned short*)(ws + 0);          // N*128 bf16 (pre-scaled)
  unsigned short* SK1 = (unsigned short*)(ws + 12800000);   // N*128 bf16
  unsigned char*  KV1 = (unsigned char*)(ws + 25600000);    // N*256 fp8
  unsigned char*  C2  = (unsigned char*)(ws + 64000000);    // N*256 bytes [Q|KV8|pad|H]
  // CSR + weights + misc
  int* rowptr = (int*)(ws + 89600000);                      // N+1
  int* esrc   = (int*)(ws + 89900032);                      // E (byte offsets, src<<8)
  int* bhist  = (int*)(ws + 93100032);                      // NBK
  int* boff   = (int*)(ws + 93101056);                      // NBK+1
  int* bcur   = (int*)(ws + 93102080);                      // NBK
  unsigned short* Wt1   = (unsigned short*)(ws + 93103104);   // 512x128 bf16
  unsigned short* Wt2   = (unsigned short*)(ws + 93234176);   // 128x128 bf16
  float*          bcat1 = (float*)(ws + 93266944);
  float*          bcat2 = (float*)(ws + 93268992);
  float*          pblock = (float*)(ws + 93269504);         // 12500 floats
  int*            ebuck = (int*)(ws + 93319552);            // E * 4B packed

  float* out = (float*)d_out;

  dim3 blk(256);

  hipMemsetAsync(bhist, 0, NBK * sizeof(int), stream);

  // ---- fused prep: weights + bucket histogram ----
  prep_fused<<<dim3(W1_B + W2_B + EB), blk, 0, stream>>>(
      Wq1, Wk1, Wv1, Ws1, bq1, bk1, bv1, bs1,
      Wq2, Wk2, Wv2, Ws2, bq2, bk2, bv2, bs2,
      Wt1, bcat1, Wt2, bcat2, ei, bhist, E);

  // ---- bucket scan ----
  bucket_scan<<<dim3(1), blk, 0, stream>>>(bhist, boff, bcur);

  // ---- FUSED: edge scatter + conv1 GEMM (independent; run concurrently) ----
  scatter_gemm1<<<dim3(EB + GB), blk, 0, stream>>>(
      ei, bcur, ebuck, E, EB, x, Wt1, bcat1, Q1b, SK1, KV1, N);

  // ---- per-bucket CSR finalize ----
  bucket_csr<<<dim3(NBK), blk, 0, stream>>>(ebuck, boff, rowptr, esrc, N);

  // ---- FUSED: conv1 attention + conv2 GEMM (H stays in LDS) ----
  attn1_gemm2<<<dim3(GB2), blk, 0, stream>>>(
      rowptr, esrc, Q1b, KV1, SK1, Wt2, bcat2, C2, N);

  // ---- conv2 attention + fused relu/mean/Wo-dot -> per-block partials ----
  node_attn2<<<dim3(AB), blk, 0, stream>>>(rowptr, esrc, C2, Wo, pblock, N);

  // ---- final reduce ----
  final_out<<<dim3(1), blk, 0, stream>>>(pblock, bo, out, AB, 1.0f / (float)N);
}

// Round 5
// 240.658 us; speedup vs baseline: 1.0760x; 1.0760x over previous
//
#include <hip/hip_runtime.h>
#include <math.h>

#define N_NODES 50000
#define N_EDGES 800000
#define NBK 196          // dst buckets of 256 nodes: bucket = dst >> 8
#define BCAP 6144        // max edges per bucket handled in LDS (mean 4082, sigma 64)

typedef short short8 __attribute__((ext_vector_type(8)));
typedef float f32x4 __attribute__((ext_vector_type(4)));
typedef float f32x2 __attribute__((ext_vector_type(2)));

// ---------------- bf16 / fp8 helpers ----------------
__device__ inline unsigned short f2bf(float v) {
  unsigned u = __float_as_uint(v);
  u += 0x7FFFu + ((u >> 16) & 1u);  // round-to-nearest-even
  return (unsigned short)(u >> 16);
}
__device__ inline float bf2f(unsigned short b) {
  return __uint_as_float(((unsigned)b) << 16);
}
__device__ inline float bflo(unsigned u) { return __uint_as_float(u << 16); }
__device__ inline float bfhi(unsigned u) { return __uint_as_float(u & 0xFFFF0000u); }
// fp8 e4m3 (OCP on gfx950); decode selector must be an immediate -> template param.
__device__ inline unsigned char f2fp8(float v) {
  return (unsigned char)(__builtin_amdgcn_cvt_pk_fp8_f32(v, 0.f, 0, false) & 0xFF);
}
template <bool HI>
__device__ inline f32x2 fp8dec(unsigned u) {
  return __builtin_amdgcn_cvt_pk_f32_fp8(u, HI);
}

#define SCL 0.17677669529663687f   // 1/sqrt(32), folded into Wq/bq at prep

// ---------------- fused prep: weight concat/transpose + bucket histogram ----------------
#define W1_B 256      // 512*128 / 256
#define W2_B 64       // 128*128 / 256
__global__ void prep_fused(const float* __restrict__ Wq1, const float* __restrict__ Wk1,
                           const float* __restrict__ Wv1, const float* __restrict__ Ws1,
                           const float* __restrict__ bq1, const float* __restrict__ bk1,
                           const float* __restrict__ bv1, const float* __restrict__ bs1,
                           const float* __restrict__ Wq2, const float* __restrict__ Wk2,
                           const float* __restrict__ Wv2, const float* __restrict__ Ws2,
                           const float* __restrict__ bq2, const float* __restrict__ bk2,
                           const float* __restrict__ bv2, const float* __restrict__ bs2,
                           unsigned short* __restrict__ Wt1, float* __restrict__ bcat1,
                           unsigned short* __restrict__ Wt2, float* __restrict__ bcat2,
                           const int* __restrict__ ei, int* __restrict__ bhist, int E) {
  const int b = blockIdx.x, tid = threadIdx.x;
  if (b < W1_B) {
    int i = b * 256 + tid;   // over 512*128
    int c = i >> 7, k = i & 127;
    int mi = c >> 7, lc = c & 127;
    const float* W = (mi == 0) ? Wq1 : (mi == 1) ? Wk1 : (mi == 2) ? Wv1 : Ws1;
    float scl = (mi == 0) ? SCL : 1.f;
    Wt1[i] = f2bf(W[(size_t)k * 128 + lc] * scl);
    if (i < 512) {
      int bm = i >> 7, bl = i & 127;
      const float* bb = (bm == 0) ? bq1 : (bm == 1) ? bk1 : (bm == 2) ? bv1 : bs1;
      bcat1[i] = bb[bl] * ((bm == 0) ? SCL : 1.f);
    }
  } else if (b < W1_B + W2_B) {
    int i = (b - W1_B) * 256 + tid;  // over 128*128
    int c = i >> 7, k = i & 127;
    int mi = c >> 5, lc = c & 31;
    const float* W = (mi == 0) ? Wq2 : (mi == 1) ? Wk2 : (mi == 2) ? Wv2 : Ws2;
    float scl = (mi == 0) ? SCL : 1.f;
    Wt2[i] = f2bf(W[(size_t)k * 32 + lc] * scl);
    if (i < 128) {
      int bm = i >> 5, bl = i & 31;
      const float* bb = (bm == 0) ? bq2 : (bm == 1) ? bk2 : (bm == 2) ? bv2 : bs2;
      bcat2[i] = bb[bl] * ((bm == 0) ? SCL : 1.f);
    }
  } else {
    __shared__ int h[NBK];
    for (int i = tid; i < NBK; i += 256) h[i] = 0;
    __syncthreads();
    int e = (b - W1_B - W2_B) * 4096 + tid;
#pragma unroll
    for (int p = 0; p < 16; ++p, e += 256)
      if (e < E) atomicAdd(&h[ei[E + e] >> 8], 1);
    __syncthreads();
    for (int i = tid; i < NBK; i += 256)
      if (h[i]) atomicAdd(&bhist[i], h[i]);
  }
}

// ================= bucket scan =================
__global__ void bucket_scan(const int* __restrict__ bhist, int* __restrict__ boff,
                            int* __restrict__ bcur) {
  __shared__ int s[256];
  int t = threadIdx.x;
  int v = (t < NBK) ? bhist[t] : 0;
  s[t] = v;
  __syncthreads();
#pragma unroll
  for (int off = 1; off < 256; off <<= 1) {
    int u = (t >= off) ? s[t - off] : 0;
    __syncthreads();
    s[t] += u;
    __syncthreads();
  }
  if (t < NBK) {
    int excl = s[t] - v;
    boff[t] = excl;
    bcur[t] = excl;
  }
  if (t == NBK - 1) boff[NBK] = s[t];
}

// ================= FUSED: bucket_scatter (blocks [0,EB)) + conv1 GEMM (blocks [EB,EB+GB)) ====
// Scatter: LDS-aggregated two-phase bucket scatter -> contiguous slot chunks per block.
// GEMM: 64 rows x 512 cols in TWO 256-col passes (acc[4][4]) keeping natural VGPR well
// below the 168 hint (r2 lesson: binding caps -> catastrophic spill roulette).
// r4 lesson: do NOT barrier-fuse attention with GEMMs -- fused blocks pay max-over-waves
// edge imbalance; split kernels pay the mean (attn waves retire independently).
__global__ __launch_bounds__(256, 3) void scatter_gemm1(
    const int* __restrict__ ei, int* __restrict__ bcur, int* __restrict__ ebuck, int E, int EB,
    const float* __restrict__ X, const unsigned short* __restrict__ Wt,
    const float* __restrict__ bcat, unsigned short* __restrict__ Q1b,
    unsigned short* __restrict__ SK1, unsigned char* __restrict__ KV8, int M) {
  __shared__ __align__(16) unsigned char L[3][64 * 272];  // 52.2 KB
  const int tid = threadIdx.x;

  if ((int)blockIdx.x < EB) {
    // ---------- scatter path ----------
    int* lh = (int*)L[0];
    for (int i = tid; i < NBK; i += 256) lh[i] = 0;
    __syncthreads();
    const int e0 = blockIdx.x * 4096;
    int pks[16], bks[16];
#pragma unroll
    for (int p = 0; p < 16; ++p) {
      int e = e0 + p * 256 + tid;
      if (e < E) {
        int src = ei[e], dst = ei[E + e];
        pks[p] = (src << 8) | (dst & 255);
        bks[p] = dst >> 8;
        atomicAdd(&lh[bks[p]], 1);
      } else bks[p] = -1;
    }
    __syncthreads();
    for (int i = tid; i < NBK; i += 256)
      if (lh[i]) lh[i] = atomicAdd(&bcur[i], lh[i]);
    __syncthreads();
#pragma unroll
    for (int p = 0; p < 16; ++p) {
      if (bks[p] >= 0) {
        int slot = atomicAdd(&lh[bks[p]], 1);
        ebuck[slot] = pks[p];
      }
    }
    return;
  }

  // ---------- GEMM path (two passes, low register pressure) ----------
  unsigned short* As = (unsigned short*)L[0];             // stride 136 shorts
  const int bm = (blockIdx.x - EB) * 64;
  const int wave = tid >> 6, lane = tid & 63;
  const int lr = lane & 15, q = lane >> 4;

#pragma unroll
  for (int p = 0; p < 8; ++p) {
    int f = tid + p * 256;          // 0..2047 float4s
    int row = f >> 5, c4 = f & 31;
    int gm = bm + row; if (gm >= M) gm = 0;
    float4 v = *(const float4*)(X + (size_t)gm * 128 + c4 * 4);
    ushort4 o;
    o.x = f2bf(v.x); o.y = f2bf(v.y); o.z = f2bf(v.z); o.w = f2bf(v.w);
    *(ushort4*)&As[row * 136 + c4 * 4] = o;
  }
  __syncthreads();

#pragma unroll
  for (int pass = 0; pass < 2; ++pass) {
    const int colbase = pass * 256 + wave * 64;
    f32x4 acc[4][4];
#pragma unroll
    for (int i = 0; i < 4; ++i)
#pragma unroll
      for (int j = 0; j < 4; ++j) acc[i][j] = (f32x4){0.f, 0.f, 0.f, 0.f};

#pragma unroll
    for (int ks = 0; ks < 4; ++ks) {
      short8 af[4];
#pragma unroll
      for (int i = 0; i < 4; ++i)
        af[i] = *(short8*)&As[(i * 16 + lr) * 136 + ks * 32 + q * 8];
#pragma unroll
      for (int j = 0; j < 4; ++j) {
        short8 bf = *(const short8*)(Wt + (size_t)(colbase + j * 16 + lr) * 128 + ks * 32 + q * 8);
#pragma unroll
        for (int i = 0; i < 4; ++i)
          acc[i][j] = __builtin_amdgcn_mfma_f32_16x16x32_bf16(af[i], bf, acc[i][j], 0, 0, 0);
      }
    }

    float bj[4];
#pragma unroll
    for (int j = 0; j < 4; ++j) bj[j] = bcat[colbase + j * 16 + lr];

    if (pass == 0) {
      if (wave < 2) {          // Q cols 0..127 -> L[1] bf16
        unsigned short* Ls16 = (unsigned short*)L[1];
#pragma unroll
        for (int i = 0; i < 4; ++i)
#pragma unroll
          for (int r = 0; r < 4; ++r) {
            int row = i * 16 + q * 4 + r;
#pragma unroll
            for (int j = 0; j < 4; ++j)
              Ls16[row * 136 + wave * 64 + j * 16 + lr] = f2bf(acc[i][j][r] + bj[j]);
          }
      } else {                 // K dims 0..127 -> L[2] fp8 (voff 0)
        unsigned char* KLs = L[2];
#pragma unroll
        for (int i = 0; i < 4; ++i)
#pragma unroll
          for (int r = 0; r < 4; ++r) {
            int row = i * 16 + q * 4 + r;
#pragma unroll
            for (int j = 0; j < 4; ++j) {
              int d = (wave - 2) * 64 + j * 16 + lr;
              KLs[row * 272 + 4 * (d >> 1) + (d & 1)] = f2fp8(acc[i][j][r] + bj[j]);
            }
          }
      }
    } else {
      __syncthreads();         // all As (L[0]) reads complete before SK overwrites it
      if (wave < 2) {          // V dims 0..127 -> L[2] fp8 (voff 2)
        unsigned char* KLs = L[2];
#pragma unroll
        for (int i = 0; i < 4; ++i)
#pragma unroll
          for (int r = 0; r < 4; ++r) {
            int row = i * 16 + q * 4 + r;
#pragma unroll
            for (int j = 0; j < 4; ++j) {
              int d = wave * 64 + j * 16 + lr;
              KLs[row * 272 + 4 * (d >> 1) + 2 + (d & 1)] = f2fp8(acc[i][j][r] + bj[j]);
            }
          }
      } else {                 // SK cols 0..127 -> L[0] bf16 (As no longer needed)
        unsigned short* Ls16 = (unsigned short*)L[0];
#pragma unroll
        for (int i = 0; i < 4; ++i)
#pragma unroll
          for (int r = 0; r < 4; ++r) {
            int row = i * 16 + q * 4 + r;
#pragma unroll
            for (int j = 0; j < 4; ++j)
              Ls16[row * 136 + (wave - 2) * 64 + j * 16 + lr] = f2bf(acc[i][j][r] + bj[j]);
          }
      }
    }
  }
  __syncthreads();

#pragma unroll
  for (int p = 0; p < 4; ++p) {
    int f = tid + p * 256;
    int row = f >> 4, u = f & 15;
    int gr = bm + row;
    if (gr < M) {
      *(uint4*)(Q1b + (size_t)gr * 128 + u * 8) = *(uint4*)&((unsigned short*)L[1])[row * 136 + u * 8];
      *(uint4*)(KV8 + (size_t)gr * 256 + u * 16) = *(uint4*)&L[2][row * 272 + u * 16];
      *(uint4*)(SK1 + (size_t)gr * 128 + u * 8) = *(uint4*)&((unsigned short*)L[0])[row * 136 + u * 8];
    }
  }
}

// esrc stores src<<8 (byte offset into the 256B/node tables)
__global__ void bucket_csr(const int* __restrict__ ebuck, const int* __restrict__ boff,
                           int* __restrict__ rowptr, int* __restrict__ esrc, int N) {
  const int b = blockIdx.x;
  const int lo = boff[b], hi = boff[b + 1];
  const int cnt = hi - lo;
  __shared__ int hist[256];
  __shared__ int cur[256];
  __shared__ int sorted[BCAP];
  const int t = threadIdx.x;
  hist[t] = 0;
  __syncthreads();
  for (int i = t; i < cnt; i += 256) atomicAdd(&hist[ebuck[lo + i] & 255], 1);
  __syncthreads();
  int v = hist[t];
  sorted[t] = v;
  __syncthreads();
#pragma unroll
  for (int off = 1; off < 256; off <<= 1) {
    int u = (t >= off) ? sorted[t - off] : 0;
    __syncthreads();
    sorted[t] += u;
    __syncthreads();
  }
  int excl = sorted[t] - v;
  cur[t] = excl;
  int node = b * 256 + t;
  if (node <= N) rowptr[node] = lo + excl;
  __syncthreads();
  for (int i = t; i < cnt; i += 256) {
    int pk = ebuck[lo + i];
    int slot = atomicAdd(&cur[pk & 255], 1);
    if (slot < BCAP) sorted[slot] = pk;
    else esrc[lo + slot] = pk & 0xFFFFFF00;
  }
  __syncthreads();
  int lim = cnt < BCAP ? cnt : BCAP;
  for (int i = t; i < lim; i += 256) esrc[lo + i] = sorted[i] & 0xFFFFFF00;
}

// ---- gemm2: LDS-staged A (bf16); 128 cols -> C2 rows (256 B): [Q bf16 | KV fp8 | pad | H bf16] ----
__global__ __launch_bounds__(256) void gemm2(
    const unsigned short* __restrict__ Ab, const unsigned short* __restrict__ Wt,
    const float* __restrict__ bcat, unsigned char* __restrict__ C2b, int M) {
  __shared__ __align__(16) unsigned short As[64 * 136];
  __shared__ __align__(16) unsigned char Lsb[64 * 272];
  const int bm = blockIdx.x * 64;
  const int tid = threadIdx.x, wave = tid >> 6, lane = tid & 63;
  const int lr = lane & 15, q = lane >> 4;

#pragma unroll
  for (int p = 0; p < 4; ++p) {
    int f = tid + p * 256;
    int row = f >> 4, chunk = f & 15;
    int gm = bm + row; if (gm >= M) gm = 0;
    uint4 v = *(const uint4*)(Ab + (size_t)gm * 128 + chunk * 8);
    *(uint4*)&As[row * 136 + chunk * 8] = v;
  }
  __syncthreads();

  f32x4 acc[4][2];
#pragma unroll
  for (int i = 0; i < 4; ++i)
#pragma unroll
    for (int j = 0; j < 2; ++j) acc[i][j] = (f32x4){0.f, 0.f, 0.f, 0.f};

#pragma unroll
  for (int ks = 0; ks < 4; ++ks) {
    short8 af[4];
#pragma unroll
    for (int i = 0; i < 4; ++i)
      af[i] = *(short8*)&As[(i * 16 + lr) * 136 + ks * 32 + q * 8];
#pragma unroll
    for (int j = 0; j < 2; ++j) {
      short8 bf = *(const short8*)(Wt + (size_t)(wave * 32 + j * 16 + lr) * 128 + ks * 32 + q * 8);
#pragma unroll
      for (int i = 0; i < 4; ++i)
        acc[i][j] = __builtin_amdgcn_mfma_f32_16x16x32_bf16(af[i], bf, acc[i][j], 0, 0, 0);
    }
  }

  float bj[2];
#pragma unroll
  for (int j = 0; j < 2; ++j) bj[j] = bcat[wave * 32 + j * 16 + lr];
#pragma unroll
  for (int i = 0; i < 4; ++i)
#pragma unroll
    for (int r = 0; r < 4; ++r) {
      int row = i * 16 + q * 4 + r;
#pragma unroll
      for (int j = 0; j < 2; ++j) {
        int c = wave * 32 + j * 16 + lr;
        float val = acc[i][j][r] + bj[j];
        if (c < 32) {
          *(unsigned short*)&Lsb[row * 272 + 2 * c] = f2bf(val);
        } else if (c < 64) {
          int d = c - 32;
          Lsb[row * 272 + 64 + 4 * (d >> 1) + (d & 1)] = f2fp8(val);
        } else if (c < 96) {
          int d = c - 64;
          Lsb[row * 272 + 64 + 4 * (d >> 1) + 2 + (d & 1)] = f2fp8(val);
        } else {
          *(unsigned short*)&Lsb[row * 272 + 192 + 2 * (c - 96)] = f2bf(val);
        }
      }
    }
  __syncthreads();
#pragma unroll
  for (int p = 0; p < 16; ++p) {
    int idx = tid + p * 256;
    int row = idx >> 6, u = idx & 63;
    int gr = bm + row;
    if (gr < M) *(unsigned*)(C2b + (size_t)gr * 256 + u * 4) = *(const unsigned*)&Lsb[row * 272 + u * 4];
  }
}

// ================= fused aggregation: plain-exp softmax, fp8 K/V =================
// conv1: 16 lanes per edge (4 groups), uint4 (16 B/lane) KV loads -- half the VMEM
// instructions of the old 32-lane/uint2 form; 2 edges in flight per lane (ILP kept).
// Lane holds dims 8*ll..8*ll+7; head (32 dims) = 4 lanes -> dot reduce masks 1,2;
// per-head softmax preserved (l per lane = its head's denominator).
__global__ void node_attn1(const int* __restrict__ rowptr, const int* __restrict__ esrc,
                           const unsigned short* __restrict__ Qb,
                           const unsigned char* __restrict__ KV8,
                           const unsigned short* __restrict__ SK, unsigned short* __restrict__ Hb,
                           int n) {
  int node = (blockIdx.x * blockDim.x + threadIdx.x) >> 6;
  int lane = threadIdx.x & 63;
  if (node >= n) return;
  const int g = lane >> 4, ll = lane & 15;   // 4 groups x 16 lanes
  const int r0 = rowptr[node], r1 = rowptr[node + 1];
  uint4 qq = *(const uint4*)(Qb + (size_t)node * 128 + ll * 8);
  const float q0 = bflo(qq.x), q1 = bfhi(qq.x), q2 = bflo(qq.y), q3 = bfhi(qq.y);
  const float q4 = bflo(qq.z), q5 = bfhi(qq.z), q6 = bflo(qq.w), q7 = bfhi(qq.w);
  float l = 0.f;
  float a0 = 0.f, a1 = 0.f, a2 = 0.f, a3 = 0.f, a4 = 0.f, a5 = 0.f, a6 = 0.f, a7 = 0.f;
  const unsigned char* kvb = KV8 + ll * 16;
  int j = r0;
  for (; j + 8 <= r1; j += 8) {      // 8 edges/wave-iter: 4 groups x 2 edges
    int e = j + g * 2;
    int sA = esrc[e], sB = esrc[e + 1];
    uint4 uA = *(const uint4*)(kvb + sA);
    uint4 uB = *(const uint4*)(kvb + sB);
    f32x2 kA0 = fp8dec<false>(uA.x), kA1 = fp8dec<false>(uA.y),
          kA2 = fp8dec<false>(uA.z), kA3 = fp8dec<false>(uA.w);
    f32x2 kB0 = fp8dec<false>(uB.x), kB1 = fp8dec<false>(uB.y),
          kB2 = fp8dec<false>(uB.z), kB3 = fp8dec<false>(uB.w);
    float dA = q0 * kA0.x + q1 * kA0.y + q2 * kA1.x + q3 * kA1.y
             + q4 * kA2.x + q5 * kA2.y + q6 * kA3.x + q7 * kA3.y;
    float dB = q0 * kB0.x + q1 * kB0.y + q2 * kB1.x + q3 * kB1.y
             + q4 * kB2.x + q5 * kB2.y + q6 * kB3.x + q7 * kB3.y;
#pragma unroll
    for (int msk = 1; msk <= 2; msk <<= 1) {   // reduce within 4-lane heads
      dA += __shfl_xor(dA, msk);
      dB += __shfl_xor(dB, msk);
    }
    float pA = __expf(dA), pB = __expf(dB);
    l += pA + pB;
    f32x2 vA0 = fp8dec<true>(uA.x), vA1 = fp8dec<true>(uA.y),
          vA2 = fp8dec<true>(uA.z), vA3 = fp8dec<true>(uA.w);
    f32x2 vB0 = fp8dec<true>(uB.x), vB1 = fp8dec<true>(uB.y),
          vB2 = fp8dec<true>(uB.z), vB3 = fp8dec<true>(uB.w);
    a0 += pA * vA0.x + pB * vB0.x;
    a1 += pA * vA0.y + pB * vB0.y;
    a2 += pA * vA1.x + pB * vB1.x;
    a3 += pA * vA1.y + pB * vB1.y;
    a4 += pA * vA2.x + pB * vB2.x;
    a5 += pA * vA2.y + pB * vB2.y;
    a6 += pA * vA3.x + pB * vB3.x;
    a7 += pA * vA3.y + pB * vB3.y;
  }
  for (; j < r1; j += 4) {           // masked tail: 4 groups x 1 edge per pass
    int e = j + g;
    bool v = e < r1;
    int s = esrc[v ? e : r0];
    uint4 u = *(const uint4*)(kvb + s);
    f32x2 k0 = fp8dec<false>(u.x), k1 = fp8dec<false>(u.y),
          k2 = fp8dec<false>(u.z), k3 = fp8dec<false>(u.w);
    float d = q0 * k0.x + q1 * k0.y + q2 * k1.x + q3 * k1.y
            + q4 * k2.x + q5 * k2.y + q6 * k3.x + q7 * k3.y;
#pragma unroll
    for (int msk = 1; msk <= 2; msk <<= 1) d += __shfl_xor(d, msk);
    float p = v ? __expf(d) : 0.f;
    l += p;
    f32x2 v0 = fp8dec<true>(u.x), v1 = fp8dec<true>(u.y),
          v2 = fp8dec<true>(u.z), v3 = fp8dec<true>(u.w);
    a0 += p * v0.x; a1 += p * v0.y; a2 += p * v1.x; a3 += p * v1.y;
    a4 += p * v2.x; a5 += p * v2.y; a6 += p * v3.x; a7 += p * v3.y;
  }
  // cross-group combine (same ll across 4 groups)
#pragma unroll
  for (int msk = 16; msk <= 32; msk <<= 1) {
    l  += __shfl_xor(l, msk);
    a0 += __shfl_xor(a0, msk);
    a1 += __shfl_xor(a1, msk);
    a2 += __shfl_xor(a2, msk);
    a3 += __shfl_xor(a3, msk);
    a4 += __shfl_xor(a4, msk);
    a5 += __shfl_xor(a5, msk);
    a6 += __shfl_xor(a6, msk);
    a7 += __shfl_xor(a7, msk);
  }
  float inv = (l > 0.f) ? 1.f / l : 0.f;
  if (g == 0) {
    uint4 sk = *(const uint4*)(SK + (size_t)node * 128 + ll * 8);
    float o0 = fmaxf(bflo(sk.x) + a0 * inv, 0.f);
    float o1 = fmaxf(bfhi(sk.x) + a1 * inv, 0.f);
    float o2 = fmaxf(bflo(sk.y) + a2 * inv, 0.f);
    float o3 = fmaxf(bfhi(sk.y) + a3 * inv, 0.f);
    float o4 = fmaxf(bflo(sk.z) + a4 * inv, 0.f);
    float o5 = fmaxf(bfhi(sk.z) + a5 * inv, 0.f);
    float o6 = fmaxf(bflo(sk.w) + a6 * inv, 0.f);
    float o7 = fmaxf(bfhi(sk.w) + a7 * inv, 0.f);
    uint4 hb;
    hb.x = ((unsigned)f2bf(o1) << 16) | (unsigned)f2bf(o0);
    hb.y = ((unsigned)f2bf(o3) << 16) | (unsigned)f2bf(o2);
    hb.z = ((unsigned)f2bf(o5) << 16) | (unsigned)f2bf(o4);
    hb.w = ((unsigned)f2bf(o7) << 16) | (unsigned)f2bf(o6);
    *(uint4*)(Hb + (size_t)node * 128 + ll * 8) = hb;
  }
}

// conv2 + fused relu/mean/Wo-dot: 8 lanes per edge (8 groups), uint2 (8 B/lane) --
// half the VMEM instructions of the old 16-lane/uint form. Lane holds dims 4*gl..4*gl+3.
__global__ void node_attn2(const int* __restrict__ rowptr, const int* __restrict__ esrc,
                           const unsigned char* __restrict__ C2b, const float* __restrict__ Wo,
                           float* __restrict__ pblock, int n) {
  __shared__ float ps[4];
  int node = (blockIdx.x * blockDim.x + threadIdx.x) >> 6;
  int lane = threadIdx.x & 63;
  int wave = threadIdx.x >> 6;
  const int g = lane >> 3, gl = lane & 7;   // 8 groups x 8 lanes
  float t = 0.f;
  if (node < n) {
    const int r0 = rowptr[node], r1 = rowptr[node + 1];
    uint2 qu = *(const uint2*)(C2b + (size_t)node * 256 + gl * 8);
    const float q0 = bflo(qu.x), q1 = bfhi(qu.x), q2 = bflo(qu.y), q3 = bfhi(qu.y);
    float l = 0.f, a0 = 0.f, a1 = 0.f, a2 = 0.f, a3 = 0.f;
    const unsigned char* kvb = C2b + 64 + gl * 8;
    int j = r0;
    for (; j + 8 <= r1; j += 8) {    // 8 edges/wave-iter: 8 groups x 1 edge
      int s = esrc[j + g];
      uint2 u = *(const uint2*)(kvb + s);
      f32x2 k0 = fp8dec<false>(u.x), k1 = fp8dec<false>(u.y);
      float d = q0 * k0.x + q1 * k0.y + q2 * k1.x + q3 * k1.y;
#pragma unroll
      for (int msk = 1; msk <= 4; msk <<= 1) d += __shfl_xor(d, msk);
      float p = __expf(d);
      l += p;
      f32x2 v0 = fp8dec<true>(u.x), v1 = fp8dec<true>(u.y);
      a0 += p * v0.x; a1 += p * v0.y; a2 += p * v1.x; a3 += p * v1.y;
    }
    for (; j < r1; j += 8) {         // masked tail
      bool v = (j + g) < r1;
      int s = esrc[v ? j + g : r0];
      uint2 u = *(const uint2*)(kvb + s);
      f32x2 kd0 = fp8dec<false>(u.x), kd1 = fp8dec<false>(u.y);
      float d = q0 * kd0.x + q1 * kd0.y + q2 * kd1.x + q3 * kd1.y;
#pragma unroll
      for (int msk = 1; msk <= 4; msk <<= 1) d += __shfl_xor(d, msk);
      float p = v ? __expf(d) : 0.f;
      l += p;
      f32x2 vd0 = fp8dec<true>(u.x), vd1 = fp8dec<true>(u.y);
      a0 += p * vd0.x; a1 += p * vd0.y; a2 += p * vd1.x; a3 += p * vd1.y;
    }
    // cross-group combine (same gl across 8 groups)
#pragma unroll
    for (int msk = 8; msk <= 32; msk <<= 1) {
      l  += __shfl_xor(l, msk);
      a0 += __shfl_xor(a0, msk);
      a1 += __shfl_xor(a1, msk);
      a2 += __shfl_xor(a2, msk);
      a3 += __shfl_xor(a3, msk);
    }
    float inv = (l > 0.f) ? 1.f / l : 0.f;
    uint2 hu = *(const uint2*)(C2b + (size_t)node * 256 + 192 + gl * 8);
    float o0 = fmaxf(bflo(hu.x) + a0 * inv, 0.f);
    float o1 = fmaxf(bfhi(hu.x) + a1 * inv, 0.f);
    float o2 = fmaxf(bflo(hu.y) + a2 * inv, 0.f);
    float o3 = fmaxf(bfhi(hu.y) + a3 * inv, 0.f);
    t = o0 * Wo[4 * gl] + o1 * Wo[4 * gl + 1] + o2 * Wo[4 * gl + 2] + o3 * Wo[4 * gl + 3];
    // reduce over 8 gl-lanes (all groups hold identical o after cross-group combine)
#pragma unroll
    for (int msk = 1; msk <= 4; msk <<= 1) t += __shfl_xor(t, msk);
  }
  if (lane == 0) ps[wave] = t;
  __syncthreads();
  if (threadIdx.x == 0) pblock[blockIdx.x] = ps[0] + ps[1] + ps[2] + ps[3];
}

// ---------------- final: sum per-block partials, scale, bias ----------------
// (kept as a kernel: folding into node_attn2 via single-address atomics risks
//  cross-XCD serialization of 12500 atomics -- G12 -- for a ~2 us saving)
__global__ void final_out(const float* __restrict__ pblock, const float* __restrict__ bo,
                          float* __restrict__ out, int nb, float invN) {
  __shared__ float s[256];
  float acc = 0.f;
  for (int i = threadIdx.x; i < nb; i += 256) acc += pblock[i];
  s[threadIdx.x] = acc;
  __syncthreads();
  for (int off = 128; off >= 1; off >>= 1) {
    if (threadIdx.x < off) s[threadIdx.x] += s[threadIdx.x + off];
    __syncthreads();
  }
  if (threadIdx.x == 0) out[0] = s[0] * invN + bo[0];
}

extern "C" void kernel_launch(void* const* d_in, const int* in_sizes, int n_in,
                              void* d_out, int out_size, void* d_ws, size_t ws_size,
                              hipStream_t stream) {
  const float* x   = (const float*)d_in[0];
  const int*   ei  = (const int*)d_in[1];  // [2, E]: row 0 = src, row 1 = dst
  const float* Wq1 = (const float*)d_in[2];  const float* bq1 = (const float*)d_in[3];
  const float* Wk1 = (const float*)d_in[4];  const float* bk1 = (const float*)d_in[5];
  const float* Wv1 = (const float*)d_in[6];  const float* bv1 = (const float*)d_in[7];
  const float* Ws1 = (const float*)d_in[8];  const float* bs1 = (const float*)d_in[9];
  const float* Wq2 = (const float*)d_in[10]; const float* bq2 = (const float*)d_in[11];
  const float* Wk2 = (const float*)d_in[12]; const float* bk2 = (const float*)d_in[13];
  const float* Wv2 = (const float*)d_in[14]; const float* bv2 = (const float*)d_in[15];
  const float* Ws2 = (const float*)d_in[16]; const float* bs2 = (const float*)d_in[17];
  const float* Wo  = (const float*)d_in[18]; const float* bo  = (const float*)d_in[19];

  char* ws = (char*)d_ws;
  const int N = N_NODES, E = N_EDGES;
  const int GB = (N + 63) / 64;
  const int EB = (E + 4095) / 4096;
  const int AB = (N * 64) / 256;   // 12500 attn blocks

  // buffers
  unsigned short* Q1b = (unsigned short*)(ws + 0);          // N*128 bf16 (pre-scaled)
  unsigned short* SK1 = (unsigned short*)(ws + 12800000);   // N*128 bf16
  unsigned char*  KV1 = (unsigned char*)(ws + 25600000);    // N*256 fp8
  unsigned short* H1b = (unsigned short*)(ws + 51200000);   // N*128 bf16
  unsigned char*  C2  = (unsigned char*)(ws + 64000000);    // N*256 bytes [Q|KV8|pad|H]
  // CSR + weights + misc
  int* rowptr = (int*)(ws + 89600000);                      // N+1
  int* esrc   = (int*)(ws + 89900032);                      // E (byte offsets, src<<8)
  int* bhist  = (int*)(ws + 93100032);                      // NBK
  int* boff   = (int*)(ws + 93101056);                      // NBK+1
  int* bcur   = (int*)(ws + 93102080);                      // NBK
  unsigned short* Wt1   = (unsigned short*)(ws + 93103104);   // 512x128 bf16
  unsigned short* Wt2   = (unsigned short*)(ws + 93234176);   // 128x128 bf16
  float*          bcat1 = (float*)(ws + 93266944);
  float*          bcat2 = (float*)(ws + 93268992);
  float*          pblock = (float*)(ws + 93269504);         // 12500 floats
  int*            ebuck = (int*)(ws + 93319552);            // E * 4B packed

  float* out = (float*)d_out;

  dim3 blk(256);

  hipMemsetAsync(bhist, 0, NBK * sizeof(int), stream);

  // ---- fused prep: weights + bucket histogram ----
  prep_fused<<<dim3(W1_B + W2_B + EB), blk, 0, stream>>>(
      Wq1, Wk1, Wv1, Ws1, bq1, bk1, bv1, bs1,
      Wq2, Wk2, Wv2, Ws2, bq2, bk2, bv2, bs2,
      Wt1, bcat1, Wt2, bcat2, ei, bhist, E);

  // ---- bucket scan ----
  bucket_scan<<<dim3(1), blk, 0, stream>>>(bhist, boff, bcur);

  // ---- FUSED: edge scatter + conv1 GEMM (independent; run concurrently) ----
  scatter_gemm1<<<dim3(EB + GB), blk, 0, stream>>>(
      ei, bcur, ebuck, E, EB, x, Wt1, bcat1, Q1b, SK1, KV1, N);

  // ---- per-bucket CSR finalize ----
  bucket_csr<<<dim3(NBK), blk, 0, stream>>>(ebuck, boff, rowptr, esrc, N);

  // ---- conv1 fused attention + skip + relu -> bf16 ----
  node_attn1<<<dim3(AB), blk, 0, stream>>>(rowptr, esrc, Q1b, KV1, SK1, H1b, N);

  // ---- conv2 GEMM (fused Q|KV8|H rows) ----
  gemm2<<<dim3(GB), blk, 0, stream>>>(H1b, Wt2, bcat2, C2, N);

  // ---- conv2 attention + fused relu/mean/Wo-dot -> per-block partials ----
  node_attn2<<<dim3(AB), blk, 0, stream>>>(rowptr, esrc, C2, Wo, pblock, N);

  // ---- final reduce ----
  final_out<<<dim3(1), blk, 0, stream>>>(pblock, bo, out, AB, 1.0f / (float)N);
}